// Round 4
// baseline (1945.083 us; speedup 1.0000x reference)
//
#include <hip/hip_runtime.h>
#include <math.h>

#define N_USERS_C 100000
#define N_ITEMS_C 50000
#define N_NODES_C 150000
#define N_EDGES_C 2000000
#define N_ENTRIES_C 4000000
#define DIM_C 64
#define DECAY_C 1e-4f
#define BATCH_C 4096

#define NBUCK 1172        // buckets of 128 nodes: 1172*128 = 150016
#define DEPTH 6           // staging depth per bucket in partition kernel
#define TILE_EDGES 2048   // edges per partition block
#define NTILES ((N_EDGES_C + TILE_EDGES - 1) / TILE_EDGES)  // 977

// ws layout (4-byte units): entries[4M int2] | cnt[1184] | off[1184] | cur[1184] | acc
#define WS_ENT 0
#define WS_CNT (2 * N_ENTRIES_C)
#define WS_OFF (WS_CNT + 1184)
#define WS_CUR (WS_OFF + 1184)
#define WS_ACC (WS_CUR + 1184)

// ---------------------------------------------------------------------------
// Pass A: bucket histogram (per-block LDS hist, one flush per bucket)
// ---------------------------------------------------------------------------
__global__ __launch_bounds__(256) void hist_kernel(
    const int* __restrict__ edge_row, const int* __restrict__ edge_col,
    int* __restrict__ cnt) {
  __shared__ int h[NBUCK];
  const int tid = threadIdx.x;
  for (int i = tid; i < NBUCK; i += 256) h[i] = 0;
  __syncthreads();
  const int base = blockIdx.x * TILE_EDGES;
  #pragma unroll
  for (int k = 0; k < 8; ++k) {
    int e = base + k * 256 + tid;
    if (e < N_EDGES_C) {
      atomicAdd(&h[edge_row[e] >> 7], 1);
      atomicAdd(&h[(N_USERS_C + edge_col[e]) >> 7], 1);
    }
  }
  __syncthreads();
  for (int i = tid; i < NBUCK; i += 256) {
    int v = h[i];
    if (v) atomicAdd(&cnt[i], v);
  }
}

// ---------------------------------------------------------------------------
// Pass B: exclusive scan of 1172 bucket counts (single block)
// ---------------------------------------------------------------------------
__global__ __launch_bounds__(256) void scan_kernel(
    const int* __restrict__ cnt, int* __restrict__ off, int* __restrict__ cur) {
  __shared__ int ts[256];
  const int tid = threadIdx.x;
  const int base = tid * 5;
  int v[5];
  int s = 0;
  #pragma unroll
  for (int i = 0; i < 5; ++i) {
    int idx = base + i;
    int c = (idx < NBUCK) ? cnt[idx] : 0;
    v[i] = s;
    s += c;
  }
  ts[tid] = s;
  __syncthreads();
  #pragma unroll
  for (int o = 1; o < 256; o <<= 1) {
    int y = (tid >= o) ? ts[tid - o] : 0;
    __syncthreads();
    ts[tid] += y;
    __syncthreads();
  }
  const int excl = ts[tid] - s;
  #pragma unroll
  for (int i = 0; i < 5; ++i) {
    int idx = base + i;
    if (idx < NBUCK) {
      int o = excl + v[i];
      off[idx] = o;
      cur[idx] = o;
    }
  }
  if (tid == 255) off[NBUCK] = N_ENTRIES_C;
}

// ---------------------------------------------------------------------------
// Pass C: LDS-binned multi-split partition. Entries packed (src | local<<17).
// Chunked flushes -> time-clustered, mostly full-line writes.
// ---------------------------------------------------------------------------
__global__ __launch_bounds__(256) void part_kernel(
    const int* __restrict__ edge_row, const int* __restrict__ edge_col,
    const float* __restrict__ edge_val, int* __restrict__ cur,
    int2* __restrict__ entries) {
  __shared__ int2 stg[NBUCK][DEPTH];  // 56.3 KB
  __shared__ int scnt[NBUCK];         // 4.7 KB
  const int tid = threadIdx.x;
  for (int i = tid; i < NBUCK; i += 256) scnt[i] = 0;
  __syncthreads();

  const int base = blockIdx.x * TILE_EDGES;
  #pragma unroll
  for (int k = 0; k < 8; ++k) {
    int e = base + k * 256 + tid;
    if (e < N_EDGES_C) {
      int r = edge_row[e];
      int c = edge_col[e];
      int vb = __float_as_int(edge_val[e]);
      // entry 1: user destination r, source item c
      int b1 = r >> 7;
      int2 E1 = make_int2(c | ((r & 127) << 17), vb);
      int s1 = atomicAdd(&scnt[b1], 1);
      if (s1 < DEPTH) stg[b1][s1] = E1;
      else entries[atomicAdd(&cur[b1], 1)] = E1;
      // entry 2: item destination, source user r
      int n2 = N_USERS_C + c;
      int b2 = n2 >> 7;
      int2 E2 = make_int2(r | ((n2 & 127) << 17), vb);
      int s2 = atomicAdd(&scnt[b2], 1);
      if (s2 < DEPTH) stg[b2][s2] = E2;
      else entries[atomicAdd(&cur[b2], 1)] = E2;
    }
  }
  __syncthreads();
  // flush staged chunks
  for (int i = tid; i < NBUCK; i += 256) {
    int c = scnt[i];
    if (c > DEPTH) c = DEPTH;
    if (c) {
      int p = atomicAdd(&cur[i], c);
      for (int j = 0; j < c; ++j) entries[p + j] = stg[i][j];
    }
  }
}

// ---------------------------------------------------------------------------
// Gather: block = bucket (128 nodes). Quarter-wave per entry; LDS f32 atomic
// accumulate into padded agg tile; dump tile into out's ego slots (scratch).
// ---------------------------------------------------------------------------
__global__ __launch_bounds__(256) void gather_kernel(
    const float* __restrict__ user_emb, const float* __restrict__ item_emb,
    const int* __restrict__ off, const int2* __restrict__ entries,
    float* __restrict__ out) {
  __shared__ float aggS[128 * 68];  // pad 68 -> rotates bank sets per row
  const int tid = threadIdx.x;
  const int wave = tid >> 6;
  const int lane = tid & 63;
  const int ql = lane & 15;
  const int b = blockIdx.x;

  for (int i = tid; i < 128 * 68; i += 256) aggS[i] = 0.f;
  __syncthreads();

  const int i0 = off[b];
  const int i1 = off[b + 1];

  for (int basei = i0 + wave * 64; basei < i1; basei += 256) {
    int idx = basei + lane;
    int2 E = (idx < i1) ? entries[idx] : make_int2(0, 0);
    #pragma unroll
    for (int j = 0; j < 16; ++j) {
      const int srcLane = (lane & 48) + j;
      int m = __shfl(E.x, srcLane);
      int vb = __shfl(E.y, srcLane);
      if (basei + srcLane < i1) {
        int local = m >> 17;
        int src = m & 131071;
        int nodeAbs = (b << 7) + local;
        const float* __restrict__ T = (nodeAbs < N_USERS_C) ? item_emb : user_emb;
        float4 r = *(const float4*)(T + ((size_t)src << 6) + (ql << 2));
        float v = __int_as_float(vb);
        float* ap = &aggS[local * 68 + ql * 4];
        atomicAdd(ap + 0, v * r.x);
        atomicAdd(ap + 1, v * r.y);
        atomicAdd(ap + 2, v * r.z);
        atomicAdd(ap + 3, v * r.w);
      }
    }
  }
  __syncthreads();

  // dump agg tile into out ego slots (scratch for transform)
  for (int k = tid; k < 2048; k += 256) {
    int row = k >> 4;
    int c4 = k & 15;
    int n = (b << 7) + row;
    if (n < N_NODES_C) {
      float4 val = *(const float4*)&aggS[row * 68 + c4 * 4];
      *(float4*)&out[1 + (size_t)n * 256 + c4 * 4] = val;
    }
  }
}

// ---------------------------------------------------------------------------
// Transform: block = 32 nodes (8/wave). Stage agg from ego slots, write true
// ego, then 3 layers (W staged per layer) + leakyrelu + l2norm.
// ---------------------------------------------------------------------------
__global__ __launch_bounds__(256) void transform_kernel(
    const float* __restrict__ user_emb, const float* __restrict__ item_emb,
    const float* __restrict__ W, const float* __restrict__ bvec,
    float* __restrict__ out) {
  __shared__ float Wl[DIM_C * DIM_C];  // 16 KB
  __shared__ float aggS[32][DIM_C];    // 8 KB
  const int tid = threadIdx.x;
  const int wave = tid >> 6;
  const int lane = tid & 63;
  const int n0 = blockIdx.x * 32;

  // stage agg rows from ego slots
  for (int k = tid; k < 512; k += 256) {
    int row = k >> 4;
    int c4 = k & 15;
    int n = n0 + row;
    float4 a = make_float4(0.f, 0.f, 0.f, 0.f);
    if (n < N_NODES_C) a = *(const float4*)&out[1 + (size_t)n * 256 + c4 * 4];
    *(float4*)&aggS[row][c4 * 4] = a;
  }
  __syncthreads();

  // overwrite ego slots with true ego embeddings
  #pragma unroll
  for (int j = 0; j < 8; ++j) {
    int n = n0 + wave * 8 + j;
    if (n < N_NODES_C) {
      float e = (n < N_USERS_C) ? user_emb[(size_t)n * DIM_C + lane]
                                : item_emb[(size_t)(n - N_USERS_C) * DIM_C + lane];
      __builtin_nontemporal_store(e, &out[1 + (size_t)n * 256 + lane]);
    }
  }

  for (int l = 0; l < 3; ++l) {
    __syncthreads();
    {
      const float4* Wg = (const float4*)(W + l * DIM_C * DIM_C);
      float4* Wd = (float4*)Wl;
      #pragma unroll
      for (int i = 0; i < 4; ++i) Wd[tid + i * 256] = Wg[tid + i * 256];
    }
    __syncthreads();

    const float bias = bvec[l * DIM_C + lane];
    float acc[8];
    #pragma unroll
    for (int j = 0; j < 8; ++j) acc[j] = bias;

    #pragma unroll 4
    for (int k4 = 0; k4 < 16; ++k4) {
      const float w0 = Wl[(k4 * 4 + 0) * DIM_C + lane];
      const float w1 = Wl[(k4 * 4 + 1) * DIM_C + lane];
      const float w2 = Wl[(k4 * 4 + 2) * DIM_C + lane];
      const float w3 = Wl[(k4 * 4 + 3) * DIM_C + lane];
      #pragma unroll
      for (int j = 0; j < 8; ++j) {
        const float4 a = *(const float4*)&aggS[wave * 8 + j][k4 * 4];
        acc[j] += a.x * w0 + a.y * w1 + a.z * w2 + a.w * w3;
      }
    }

    #pragma unroll
    for (int j = 0; j < 8; ++j) {
      int n = n0 + wave * 8 + j;
      float s = acc[j];
      s = (s >= 0.f) ? s : 0.2f * s;
      float q = s * s;
      #pragma unroll
      for (int o = 32; o; o >>= 1) q += __shfl_xor(q, o);
      if (n < N_NODES_C) {
        float val = s / fmaxf(sqrtf(q), 1e-12f);
        __builtin_nontemporal_store(
            val, &out[1 + (size_t)n * 256 + (size_t)(l + 1) * 64 + lane]);
      }
    }
  }
}

// ---------------------------------------------------------------------------
// Loss + finalize
// ---------------------------------------------------------------------------
__global__ __launch_bounds__(256) void loss_kernel(
    const float* __restrict__ out, const int* __restrict__ bu,
    const int* __restrict__ bp, const int* __restrict__ bn,
    float* __restrict__ acc) {
  const int wave = threadIdx.x >> 6;
  const int lane = threadIdx.x & 63;
  const int j = blockIdx.x * 4 + wave;
  if (j >= BATCH_C) return;

  const float* urow = out + 1 + (size_t)bu[j] * 256;
  const float* prow = out + 1 + ((size_t)N_USERS_C + bp[j]) * 256;
  const float* nrow = out + 1 + ((size_t)N_USERS_C + bn[j]) * 256;

  float4 u = ((const float4*)urow)[lane];
  float4 pp = ((const float4*)prow)[lane];
  float4 nn = ((const float4*)nrow)[lane];

  float x = u.x * (pp.x - nn.x) + u.y * (pp.y - nn.y) +
            u.z * (pp.z - nn.z) + u.w * (pp.w - nn.w);
  float r = u.x * u.x + u.y * u.y + u.z * u.z + u.w * u.w +
            pp.x * pp.x + pp.y * pp.y + pp.z * pp.z + pp.w * pp.w +
            nn.x * nn.x + nn.y * nn.y + nn.z * nn.z + nn.w * nn.w;

  #pragma unroll
  for (int o = 32; o; o >>= 1) {
    x += __shfl_xor(x, o);
    r += __shfl_xor(r, o);
  }
  if (lane == 0) {
    float ls = fminf(x, 0.f) - log1pf(expf(-fabsf(x)));
    atomicAdd(&acc[0], -ls);
    atomicAdd(&acc[1], 0.5f * r);
  }
}

__global__ void finalize_kernel(const float* __restrict__ acc,
                                float* __restrict__ out) {
  out[0] = acc[0] / (float)BATCH_C + DECAY_C * acc[1] / (float)BATCH_C;
}

// ---------------------------------------------------------------------------
extern "C" void kernel_launch(void* const* d_in, const int* in_sizes, int n_in,
                              void* d_out, int out_size, void* d_ws, size_t ws_size,
                              hipStream_t stream) {
  const float* user_emb = (const float*)d_in[0];
  const float* item_emb = (const float*)d_in[1];
  const float* edge_val = (const float*)d_in[2];
  const float* W        = (const float*)d_in[3];
  const float* bvec     = (const float*)d_in[4];
  const int* edge_row   = (const int*)d_in[5];
  const int* edge_col   = (const int*)d_in[6];
  const int* bu         = (const int*)d_in[7];
  const int* bp         = (const int*)d_in[8];
  const int* bn         = (const int*)d_in[9];

  float* out = (float*)d_out;
  int* ws = (int*)d_ws;
  int2* entries = (int2*)(ws + WS_ENT);
  int*  cnt = ws + WS_CNT;
  int*  off = ws + WS_OFF;
  int*  cur = ws + WS_CUR;
  float* acc = (float*)(ws + WS_ACC);

  // zero cnt/off/cur/acc in one shot
  hipMemsetAsync(cnt, 0, (size_t)(1184 * 3 + 16) * sizeof(int), stream);

  hist_kernel<<<NTILES, 256, 0, stream>>>(edge_row, edge_col, cnt);
  scan_kernel<<<1, 256, 0, stream>>>(cnt, off, cur);
  part_kernel<<<NTILES, 256, 0, stream>>>(edge_row, edge_col, edge_val, cur, entries);
  gather_kernel<<<NBUCK, 256, 0, stream>>>(user_emb, item_emb, off, entries, out);
  transform_kernel<<<(N_NODES_C + 31) / 32, 256, 0, stream>>>(
      user_emb, item_emb, W, bvec, out);
  loss_kernel<<<BATCH_C / 4, 256, 0, stream>>>(out, bu, bp, bn, acc);
  finalize_kernel<<<1, 1, 0, stream>>>(acc, out);
}

// Round 5
// 736.958 us; speedup vs baseline: 2.6393x; 2.6393x over previous
//
#include <hip/hip_runtime.h>
#include <math.h>

#define N_USERS_C 100000
#define N_ITEMS_C 50000
#define N_NODES_C 150000
#define N_EDGES_C 2000000
#define N_ENTRIES_C 4000000
#define DIM_C 64
#define DECAY_C 1e-4f
#define BATCH_C 4096

#define SCAN_ELEMS 2048
#define SCAN_NB ((N_NODES_C + SCAN_ELEMS - 1) / SCAN_ELEMS)  // 74

#define TILE_EDGES 2048
#define NTILES ((N_EDGES_C + TILE_EDGES - 1) / TILE_EDGES)   // 977
#define RANGE_NODES 18752   // 8 * 18752 = 150016 >= N_NODES

// ws layout (4-byte units): cnt[150016] | off[150032] | cur[150016] |
//                           bsum[256] | acc[16] | entries[4M int2]
#define WS_CNT 0
#define WS_OFF 150016
#define WS_CUR 300048
#define WS_BSUM 450064
#define WS_ACC 450320
#define WS_ENT 450336

// ---------------------------------------------------------------------------
// Kernel 1: per-node degree histogram (4M device atomics on 150k counters)
// ---------------------------------------------------------------------------
__global__ __launch_bounds__(256) void hist_kernel(
    const int* __restrict__ edge_row, const int* __restrict__ edge_col,
    int* __restrict__ cnt) {
  int e = blockIdx.x * blockDim.x + threadIdx.x;
  if (e >= N_EDGES_C) return;
  atomicAdd(&cnt[edge_row[e]], 1);
  atomicAdd(&cnt[N_USERS_C + edge_col[e]], 1);
}

// ---------------------------------------------------------------------------
// Kernel 2a/b/c: exclusive scan over 150k counts (proven round-2 structure)
// ---------------------------------------------------------------------------
__global__ __launch_bounds__(256) void scan1_kernel(
    const int* __restrict__ cnt, int* __restrict__ off, int* __restrict__ bsum) {
  __shared__ int ts[256];
  const int tid = threadIdx.x;
  const int base = blockIdx.x * SCAN_ELEMS + tid * 8;
  int v[8];
  int s = 0;
  #pragma unroll
  for (int i = 0; i < 8; ++i) {
    int idx = base + i;
    int c = (idx < N_NODES_C) ? cnt[idx] : 0;
    v[i] = s;
    s += c;
  }
  ts[tid] = s;
  __syncthreads();
  #pragma unroll
  for (int o = 1; o < 256; o <<= 1) {
    int y = (tid >= o) ? ts[tid - o] : 0;
    __syncthreads();
    ts[tid] += y;
    __syncthreads();
  }
  const int exclT = ts[tid] - s;
  #pragma unroll
  for (int i = 0; i < 8; ++i) {
    int idx = base + i;
    if (idx < N_NODES_C) off[idx] = exclT + v[i];
  }
  if (tid == 255) bsum[blockIdx.x] = ts[255];
}

__global__ void scan2_kernel(int* __restrict__ bsum) {
  if (threadIdx.x == 0 && blockIdx.x == 0) {
    int s = 0;
    for (int i = 0; i < SCAN_NB; ++i) {
      int t = bsum[i];
      bsum[i] = s;
      s += t;
    }
  }
}

__global__ __launch_bounds__(256) void scan3_kernel(
    int* __restrict__ off, int* __restrict__ cursor,
    const int* __restrict__ bsum) {
  const int base = blockIdx.x * SCAN_ELEMS + threadIdx.x * 8;
  const int add = bsum[blockIdx.x];
  #pragma unroll
  for (int i = 0; i < 8; ++i) {
    int idx = base + i;
    if (idx < N_NODES_C) {
      int o = off[idx] + add;
      off[idx] = o;
      cursor[idx] = o;
    }
  }
  if (blockIdx.x == 0 && threadIdx.x == 0) off[N_NODES_C] = N_ENTRIES_C;
}

// ---------------------------------------------------------------------------
// Kernel 3: XCD-range-partitioned CSR scatter.
// range = blockIdx & 7 (round-robins onto one XCD); block writes only
// entries destined to its 18752-node range -> ~4 MB CSR span, L2-resident
// on that XCD -> full-line writebacks instead of 64B-per-8B amplification.
// ---------------------------------------------------------------------------
__global__ __launch_bounds__(256) void csr_scatter_kernel(
    const int* __restrict__ edge_row, const int* __restrict__ edge_col,
    const float* __restrict__ edge_val, int* __restrict__ cursor,
    int2* __restrict__ entries) {
  const int r = blockIdx.x & 7;
  const int tile = blockIdx.x >> 3;
  const int lo = r * RANGE_NODES;
  const int hi = lo + RANGE_NODES;
  const int base = tile * TILE_EDGES;
  #pragma unroll
  for (int k = 0; k < 8; ++k) {
    int e = base + k * 256 + threadIdx.x;
    if (e < N_EDGES_C) {
      int row = edge_row[e];
      int col = edge_col[e];
      int vb = __float_as_int(edge_val[e]);
      if (row >= lo && row < hi) {
        int p = atomicAdd(&cursor[row], 1);
        entries[p] = make_int2(col, vb);
      }
      int d2 = N_USERS_C + col;
      if (d2 >= lo && d2 < hi) {
        int p = atomicAdd(&cursor[d2], 1);
        entries[p] = make_int2(row, vb);
      }
    }
  }
}

// ---------------------------------------------------------------------------
// Kernel 4: streaming gather, max occupancy (no LDS, low VGPR).
// One node per wave iteration; quarter-wave (16 lanes x float4) per entry,
// 2 entries in flight per quarter -> 8 row-loads in flight per wave.
// Writes agg row into out's ego slot (scratch for transform).
// ---------------------------------------------------------------------------
__global__ __launch_bounds__(256) void gather_kernel(
    const float* __restrict__ user_emb, const float* __restrict__ item_emb,
    const int* __restrict__ off, const int2* __restrict__ entries,
    float* __restrict__ out) {
  const int lane = threadIdx.x & 63;
  const int quarter = lane >> 4;
  const int ql = lane & 15;
  const int wave0 = (blockIdx.x * 256 + threadIdx.x) >> 6;
  const int nWaves = gridDim.x * 4;

  for (int n = wave0; n < N_NODES_C; n += nWaves) {
    const float* __restrict__ T = (n < N_USERS_C) ? item_emb : user_emb;
    int i = off[n] + quarter;
    const int end = off[n + 1];
    float4 acc = make_float4(0.f, 0.f, 0.f, 0.f);
    for (; i + 4 < end; i += 8) {
      int2 e0 = entries[i];
      int2 e1 = entries[i + 4];
      float4 r0 = *(const float4*)(T + ((size_t)e0.x << 6) + (ql << 2));
      float4 r1 = *(const float4*)(T + ((size_t)e1.x << 6) + (ql << 2));
      float v0 = __int_as_float(e0.y);
      float v1 = __int_as_float(e1.y);
      acc.x += v0 * r0.x + v1 * r1.x;
      acc.y += v0 * r0.y + v1 * r1.y;
      acc.z += v0 * r0.z + v1 * r1.z;
      acc.w += v0 * r0.w + v1 * r1.w;
    }
    if (i < end) {
      int2 e0 = entries[i];
      float4 r0 = *(const float4*)(T + ((size_t)e0.x << 6) + (ql << 2));
      float v0 = __int_as_float(e0.y);
      acc.x += v0 * r0.x;
      acc.y += v0 * r0.y;
      acc.z += v0 * r0.z;
      acc.w += v0 * r0.w;
    }
    // combine the 4 quarters
    acc.x += __shfl_xor(acc.x, 16); acc.x += __shfl_xor(acc.x, 32);
    acc.y += __shfl_xor(acc.y, 16); acc.y += __shfl_xor(acc.y, 32);
    acc.z += __shfl_xor(acc.z, 16); acc.z += __shfl_xor(acc.z, 32);
    acc.w += __shfl_xor(acc.w, 16); acc.w += __shfl_xor(acc.w, 32);
    if (lane < 16) *(float4*)&out[1 + (size_t)n * 256 + (ql << 2)] = acc;
  }
}

// ---------------------------------------------------------------------------
// Kernel 5: transform (round-4 version, proven). Block = 32 nodes (8/wave).
// ---------------------------------------------------------------------------
__global__ __launch_bounds__(256) void transform_kernel(
    const float* __restrict__ user_emb, const float* __restrict__ item_emb,
    const float* __restrict__ W, const float* __restrict__ bvec,
    float* __restrict__ out) {
  __shared__ float Wl[DIM_C * DIM_C];  // 16 KB
  __shared__ float aggS[32][DIM_C];    // 8 KB
  const int tid = threadIdx.x;
  const int wave = tid >> 6;
  const int lane = tid & 63;
  const int n0 = blockIdx.x * 32;

  for (int k = tid; k < 512; k += 256) {
    int row = k >> 4;
    int c4 = k & 15;
    int n = n0 + row;
    float4 a = make_float4(0.f, 0.f, 0.f, 0.f);
    if (n < N_NODES_C) a = *(const float4*)&out[1 + (size_t)n * 256 + c4 * 4];
    *(float4*)&aggS[row][c4 * 4] = a;
  }
  __syncthreads();

  #pragma unroll
  for (int j = 0; j < 8; ++j) {
    int n = n0 + wave * 8 + j;
    if (n < N_NODES_C) {
      float e = (n < N_USERS_C) ? user_emb[(size_t)n * DIM_C + lane]
                                : item_emb[(size_t)(n - N_USERS_C) * DIM_C + lane];
      __builtin_nontemporal_store(e, &out[1 + (size_t)n * 256 + lane]);
    }
  }

  for (int l = 0; l < 3; ++l) {
    __syncthreads();
    {
      const float4* Wg = (const float4*)(W + l * DIM_C * DIM_C);
      float4* Wd = (float4*)Wl;
      #pragma unroll
      for (int i = 0; i < 4; ++i) Wd[tid + i * 256] = Wg[tid + i * 256];
    }
    __syncthreads();

    const float bias = bvec[l * DIM_C + lane];
    float acc[8];
    #pragma unroll
    for (int j = 0; j < 8; ++j) acc[j] = bias;

    #pragma unroll 4
    for (int k4 = 0; k4 < 16; ++k4) {
      const float w0 = Wl[(k4 * 4 + 0) * DIM_C + lane];
      const float w1 = Wl[(k4 * 4 + 1) * DIM_C + lane];
      const float w2 = Wl[(k4 * 4 + 2) * DIM_C + lane];
      const float w3 = Wl[(k4 * 4 + 3) * DIM_C + lane];
      #pragma unroll
      for (int j = 0; j < 8; ++j) {
        const float4 a = *(const float4*)&aggS[wave * 8 + j][k4 * 4];
        acc[j] += a.x * w0 + a.y * w1 + a.z * w2 + a.w * w3;
      }
    }

    #pragma unroll
    for (int j = 0; j < 8; ++j) {
      int n = n0 + wave * 8 + j;
      float s = acc[j];
      s = (s >= 0.f) ? s : 0.2f * s;
      float q = s * s;
      #pragma unroll
      for (int o = 32; o; o >>= 1) q += __shfl_xor(q, o);
      if (n < N_NODES_C) {
        float val = s / fmaxf(sqrtf(q), 1e-12f);
        __builtin_nontemporal_store(
            val, &out[1 + (size_t)n * 256 + (size_t)(l + 1) * 64 + lane]);
      }
    }
  }
}

// ---------------------------------------------------------------------------
// Loss + finalize
// ---------------------------------------------------------------------------
__global__ __launch_bounds__(256) void loss_kernel(
    const float* __restrict__ out, const int* __restrict__ bu,
    const int* __restrict__ bp, const int* __restrict__ bn,
    float* __restrict__ acc) {
  const int wave = threadIdx.x >> 6;
  const int lane = threadIdx.x & 63;
  const int j = blockIdx.x * 4 + wave;
  if (j >= BATCH_C) return;

  const float* urow = out + 1 + (size_t)bu[j] * 256;
  const float* prow = out + 1 + ((size_t)N_USERS_C + bp[j]) * 256;
  const float* nrow = out + 1 + ((size_t)N_USERS_C + bn[j]) * 256;

  float4 u = ((const float4*)urow)[lane];
  float4 pp = ((const float4*)prow)[lane];
  float4 nn = ((const float4*)nrow)[lane];

  float x = u.x * (pp.x - nn.x) + u.y * (pp.y - nn.y) +
            u.z * (pp.z - nn.z) + u.w * (pp.w - nn.w);
  float r = u.x * u.x + u.y * u.y + u.z * u.z + u.w * u.w +
            pp.x * pp.x + pp.y * pp.y + pp.z * pp.z + pp.w * pp.w +
            nn.x * nn.x + nn.y * nn.y + nn.z * nn.z + nn.w * nn.w;

  #pragma unroll
  for (int o = 32; o; o >>= 1) {
    x += __shfl_xor(x, o);
    r += __shfl_xor(r, o);
  }
  if (lane == 0) {
    float ls = fminf(x, 0.f) - log1pf(expf(-fabsf(x)));
    atomicAdd(&acc[0], -ls);
    atomicAdd(&acc[1], 0.5f * r);
  }
}

__global__ void finalize_kernel(const float* __restrict__ acc,
                                float* __restrict__ out) {
  out[0] = acc[0] / (float)BATCH_C + DECAY_C * acc[1] / (float)BATCH_C;
}

// ---------------------------------------------------------------------------
extern "C" void kernel_launch(void* const* d_in, const int* in_sizes, int n_in,
                              void* d_out, int out_size, void* d_ws, size_t ws_size,
                              hipStream_t stream) {
  const float* user_emb = (const float*)d_in[0];
  const float* item_emb = (const float*)d_in[1];
  const float* edge_val = (const float*)d_in[2];
  const float* W        = (const float*)d_in[3];
  const float* bvec     = (const float*)d_in[4];
  const int* edge_row   = (const int*)d_in[5];
  const int* edge_col   = (const int*)d_in[6];
  const int* bu         = (const int*)d_in[7];
  const int* bp         = (const int*)d_in[8];
  const int* bn         = (const int*)d_in[9];

  float* out = (float*)d_out;
  int* ws = (int*)d_ws;
  int*  cnt    = ws + WS_CNT;
  int*  off    = ws + WS_OFF;
  int*  cursor = ws + WS_CUR;
  int*  bsum   = ws + WS_BSUM;
  float* acc   = (float*)(ws + WS_ACC);
  int2* entries = (int2*)(ws + WS_ENT);

  hipMemsetAsync(cnt, 0, 150016 * sizeof(int), stream);
  hipMemsetAsync(acc, 0, 2 * sizeof(float), stream);

  hist_kernel<<<(N_EDGES_C + 255) / 256, 256, 0, stream>>>(edge_row, edge_col, cnt);
  scan1_kernel<<<SCAN_NB, 256, 0, stream>>>(cnt, off, bsum);
  scan2_kernel<<<1, 64, 0, stream>>>(bsum);
  scan3_kernel<<<SCAN_NB, 256, 0, stream>>>(off, cursor, bsum);
  csr_scatter_kernel<<<NTILES * 8, 256, 0, stream>>>(
      edge_row, edge_col, edge_val, cursor, entries);
  gather_kernel<<<2048, 256, 0, stream>>>(user_emb, item_emb, off, entries, out);
  transform_kernel<<<(N_NODES_C + 31) / 32, 256, 0, stream>>>(
      user_emb, item_emb, W, bvec, out);
  loss_kernel<<<BATCH_C / 4, 256, 0, stream>>>(out, bu, bp, bn, acc);
  finalize_kernel<<<1, 1, 0, stream>>>(acc, out);
}